// Round 1
// baseline (3031.988 us; speedup 1.0000x reference)
//
#include <hip/hip_runtime.h>
#include <stdint.h>

#define NB 256  // persistent-kernel blocks == CUs

// ---------- helpers ----------
__device__ __forceinline__ float bf_lo(unsigned u) {
    union { unsigned i; float f; } v; v.i = u << 16; return v.f;
}
__device__ __forceinline__ float bf_hi(unsigned u) {
    union { unsigned i; float f; } v; v.i = u & 0xffff0000u; return v.f;
}
__device__ __forceinline__ unsigned f2bf(float f) {  // RNE round to bf16
    union { float f; unsigned i; } v; v.f = f;
    return (v.i + 0x7fffu + ((v.i >> 16) & 1u)) >> 16;
}

// device-scope grid barrier; one counter slot per barrier instance (pre-zeroed)
__device__ __forceinline__ void gbar(unsigned* ctr, int idx) {
    __syncthreads();
    if (threadIdx.x == 0) {
        __threadfence();                       // release: flush to coherence point
        atomicAdd(&ctr[idx], 1u);              // device-scope
        while (__hip_atomic_load(&ctr[idx], __ATOMIC_RELAXED,
                                 __HIP_MEMORY_SCOPE_AGENT) < NB) {
            __builtin_amdgcn_s_sleep(1);
        }
        __threadfence();                       // acquire: invalidate L1/L2 stale lines
    }
    __syncthreads();
}

// ---------- kernel G: Gx[t][j] = emb[idx[t]] . W_ih[j] + b_ih[j] + b_hh[j] ----------
// tile: 64 j x TT t; K chunks of 32. Ws stored k-major (transposed) for
// conflict-free b128 reads.
template <int TT>
__global__ __launch_bounds__(256) void gates_x_gemm(
    const int* __restrict__ idx, const float* __restrict__ emb,
    const float* __restrict__ Wih, const float* __restrict__ bih,
    const float* __restrict__ bhh, float* __restrict__ Gx) {
    __shared__ float As[TT][36];
    __shared__ float Ws[32][68];  // [k][j], padded
    const int tid = threadIdx.x;
    const int jt = blockIdx.x * 64;
    const int t0 = blockIdx.y * TT;
    constexpr int TPT = TT / 16;  // t's per thread
    const int tx = tid & 15, ty = tid >> 4;
    float acc[TPT][4];
#pragma unroll
    for (int a = 0; a < TPT; ++a)
#pragma unroll
        for (int q = 0; q < 4; ++q) acc[a][q] = 0.f;

    for (int k0 = 0; k0 < 1024; k0 += 32) {
        if constexpr (TT == 32) {
            int t = tid >> 3, kq = (tid & 7) * 4;
            int row = idx[t0 + t];
            float4 v = *(const float4*)(emb + (size_t)row * 1024 + k0 + kq);
            *(float4*)&As[t][kq] = v;
        } else {
            int t = tid >> 4, kq = (tid & 15) * 2;
            int row = idx[t0 + t];
            float2 v = *(const float2*)(emb + (size_t)row * 1024 + k0 + kq);
            *(float2*)&As[t][kq] = v;
        }
        {
            int j = tid >> 3, kq = (tid & 7) * 4;
            float4 w0 = *(const float4*)(Wih + (size_t)(jt + j) * 1024 + k0 + kq);
            float4 w1 = *(const float4*)(Wih + (size_t)(jt + j + 32) * 1024 + k0 + kq);
            const float* p0 = (const float*)&w0;
            const float* p1 = (const float*)&w1;
#pragma unroll
            for (int c = 0; c < 4; ++c) {
                Ws[kq + c][j] = p0[c];
                Ws[kq + c][j + 32] = p1[c];
            }
        }
        __syncthreads();
#pragma unroll
        for (int kk = 0; kk < 32; kk += 4) {
            float4 av[TPT];
#pragma unroll
            for (int tt = 0; tt < TPT; ++tt)
                av[tt] = *(float4*)&As[ty * TPT + tt][kk];
#pragma unroll
            for (int c = 0; c < 4; ++c) {
                float4 wv = *(float4*)&Ws[kk + c][tx * 4];
#pragma unroll
                for (int tt = 0; tt < TPT; ++tt) {
                    const float* ap = (const float*)&av[tt];
                    float a = ap[c];
                    acc[tt][0] += a * wv.x;
                    acc[tt][1] += a * wv.y;
                    acc[tt][2] += a * wv.z;
                    acc[tt][3] += a * wv.w;
                }
            }
        }
        __syncthreads();
    }
    int j = jt + tx * 4;
    float4 bi = *(const float4*)(bih + j);
    float4 bh = *(const float4*)(bhh + j);
#pragma unroll
    for (int tt = 0; tt < TPT; ++tt) {
        int t = t0 + ty * TPT + tt;
        float4 r;
        r.x = acc[tt][0] + bi.x + bh.x;
        r.y = acc[tt][1] + bi.y + bh.y;
        r.z = acc[tt][2] + bi.z + bh.z;
        r.w = acc[tt][3] + bi.w + bh.w;
        *(float4*)(Gx + (size_t)t * 8192 + j) = r;
    }
}

// ---------- kernel P: persistent LSTM scans + MLP head ----------
// 256 blocks x 512 threads; block b owns h rows [b*8, b*8+8) -> 32 gate rows
// j = g*2048 + b*8 + ml, held as bf16 in LDS (128 KB).
__global__ __launch_bounds__(512, 2) void lstm_mlp_persistent(
    const float* __restrict__ Whh_t, const float* __restrict__ Whh_a,
    const float* __restrict__ Gxt, const float* __restrict__ Gxa,
    const float* __restrict__ W1, const float* __restrict__ b1,
    const float* __restrict__ W2, const float* __restrict__ b2,
    const float* __restrict__ W3, const float* __restrict__ b3,
    unsigned* __restrict__ ctr, float* __restrict__ hbt,
    float* __restrict__ hba, float* __restrict__ h1g,
    float* __restrict__ h2g, float* __restrict__ out) {
    __shared__ unsigned short Wl[32 * 2048];  // 128 KB bf16, swizzled
    __shared__ float h_lds[2048];
    __shared__ float part[32 * 64];
    __shared__ float part2[16 * 33];
    __shared__ float gl[32];
    __shared__ float cl[8];
    const int tid = threadIdx.x;
    const int b = blockIdx.x;
    const int w = tid >> 6, l = tid & 63;
    int bar = 0;

    for (int scan = 0; scan < 2; ++scan) {
        const float* Whh = scan ? Whh_a : Whh_t;
        const float* Gx = scan ? Gxa : Gxt;
        float* hbuf = scan ? hba : hbt;
        const int T = scan ? 16 : 128;

        // load + convert W slice into LDS (swizzled so step-loop reads are
        // lane-contiguous b128): slot (rl, m, lane) holds k = (2m+hf)*256+lane*4
        {
            const int m = tid >> 7, ll = (tid >> 1) & 63, hf = tid & 1;
            for (int rl = 0; rl < 32; ++rl) {
                const int j = (rl >> 3) * 2048 + b * 8 + (rl & 7);
                float4 v = *(const float4*)(Whh + (size_t)j * 2048 +
                                            (2 * m + hf) * 256 + ll * 4);
                unsigned p0 = f2bf(v.x) | (f2bf(v.y) << 16);
                unsigned p1 = f2bf(v.z) | (f2bf(v.w) << 16);
                *(uint2*)((char*)Wl + rl * 4096 + m * 1024 + ll * 16 + hf * 8) =
                    make_uint2(p0, p1);
            }
        }
        if (tid < 8) cl[tid] = 0.f;

        for (int t = 0; t < T; ++t) {
            const float* hin = hbuf + (t & 1) * 2048;
            float* hout = hbuf + ((t + 1) & 1) * 2048;
            *(float4*)(h_lds + tid * 4) = *(const float4*)(hin + tid * 4);
            __syncthreads();
            float hreg[32];
#pragma unroll
            for (int i = 0; i < 8; ++i) {
                float4 hv = *(float4*)(h_lds + i * 256 + l * 4);
                hreg[i * 4 + 0] = hv.x;
                hreg[i * 4 + 1] = hv.y;
                hreg[i * 4 + 2] = hv.z;
                hreg[i * 4 + 3] = hv.w;
            }
#pragma unroll
            for (int r = 0; r < 4; ++r) {
                const int rl = w * 4 + r;
                float acc = 0.f;
#pragma unroll
                for (int m = 0; m < 4; ++m) {
                    uint4 u = *(uint4*)((char*)Wl + rl * 4096 + m * 1024 + l * 16);
                    const int i0 = m * 8, i1 = m * 8 + 4;
                    acc += bf_lo(u.x) * hreg[i0 + 0];
                    acc += bf_hi(u.x) * hreg[i0 + 1];
                    acc += bf_lo(u.y) * hreg[i0 + 2];
                    acc += bf_hi(u.y) * hreg[i0 + 3];
                    acc += bf_lo(u.z) * hreg[i1 + 0];
                    acc += bf_hi(u.z) * hreg[i1 + 1];
                    acc += bf_lo(u.w) * hreg[i1 + 2];
                    acc += bf_hi(u.w) * hreg[i1 + 3];
                }
                part[rl * 64 + l] = acc;
            }
            __syncthreads();
            {  // reduce 64 lane-partials per row: phase A (16 segs/row)
                const int row = tid >> 4, seg = tid & 15;
                float4 v = *(float4*)(part + row * 64 + seg * 4);
                part2[seg * 33 + row] = v.x + v.y + v.z + v.w;
            }
            __syncthreads();
            if (tid < 32) {  // phase B: final row sums + Gx
                float s = 0.f;
#pragma unroll
                for (int sg = 0; sg < 16; ++sg) s += part2[sg * 33 + tid];
                const int j = (tid >> 3) * 2048 + b * 8 + (tid & 7);
                gl[tid] = s + Gx[(size_t)t * 8192 + j];
            }
            // gate math: wave 0 lanes 0..7 (same wave as phase B, no sync needed)
            if (tid < 8) {
                float gi = gl[tid], gf = gl[8 + tid], gg = gl[16 + tid],
                      go = gl[24 + tid];
                float si = 1.f / (1.f + expf(-gi));
                float sf = 1.f / (1.f + expf(-gf));
                float tg = tanhf(gg);
                float so = 1.f / (1.f + expf(-go));
                float c = sf * cl[tid] + si * tg;
                cl[tid] = c;
                hout[b * 8 + tid] = so * tanhf(c);
            }
            gbar(ctr, bar++);
        }
    }

    // ---- MLP head: summary = [h_title(2048), h_authors(2048)] ----
    {  // h1 = relu(W1 . summary + b1): 8 rows/block, row-per-wave
        const int j = b * 8 + w;
        const float* wr = W1 + (size_t)j * 4096;
        float acc = 0.f;
#pragma unroll
        for (int i = 0; i < 32; ++i) acc += wr[l + 64 * i] * hbt[l + 64 * i];
#pragma unroll
        for (int i = 0; i < 32; ++i)
            acc += wr[2048 + l + 64 * i] * hba[l + 64 * i];
        for (int off = 32; off; off >>= 1) acc += __shfl_xor(acc, off, 64);
        if (l == 0) h1g[j] = fmaxf(acc + b1[j], 0.f);
    }
    gbar(ctr, bar++);
    {  // h2 = relu(W2 . h1 + b2)
        const int j = b * 8 + w;
        const float* wr = W2 + (size_t)j * 2048;
        float acc = 0.f;
#pragma unroll
        for (int i = 0; i < 32; ++i) acc += wr[l + 64 * i] * h1g[l + 64 * i];
        for (int off = 32; off; off >>= 1) acc += __shfl_xor(acc, off, 64);
        if (l == 0) h2g[j] = fmaxf(acc + b2[j], 0.f);
    }
    gbar(ctr, bar++);
    if (b == 0 && w < 2) {  // logits
        const float* wr = W3 + (size_t)w * 2048;
        float acc = 0.f;
#pragma unroll
        for (int i = 0; i < 32; ++i) acc += wr[l + 64 * i] * h2g[l + 64 * i];
        for (int off = 32; off; off >>= 1) acc += __shfl_xor(acc, off, 64);
        if (l == 0) out[w] = acc + b3[w];
    }
}

extern "C" void kernel_launch(void* const* d_in, const int* in_sizes, int n_in,
                              void* d_out, int out_size, void* d_ws,
                              size_t ws_size, hipStream_t stream) {
    const int* x_t = (const int*)d_in[0];
    const int* x_a = (const int*)d_in[1];
    const float* emb_t = (const float*)d_in[2];
    const float* emb_a = (const float*)d_in[3];
    const float* Wih_t = (const float*)d_in[4];
    const float* Whh_t = (const float*)d_in[5];
    const float* bih_t = (const float*)d_in[6];
    const float* bhh_t = (const float*)d_in[7];
    const float* Wih_a = (const float*)d_in[8];
    const float* Whh_a = (const float*)d_in[9];
    const float* bih_a = (const float*)d_in[10];
    const float* bhh_a = (const float*)d_in[11];
    const float* W1 = (const float*)d_in[12];
    const float* b1 = (const float*)d_in[13];
    const float* W2 = (const float*)d_in[14];
    const float* b2 = (const float*)d_in[15];
    const float* W3 = (const float*)d_in[16];
    const float* b3 = (const float*)d_in[17];

    float* ws = (float*)d_ws;
    unsigned* ctr = (unsigned*)d_ws;  // 512 slots
    float* hbt = ws + 512;            // 2 x 2048
    float* hba = ws + 4608;           // 2 x 2048
    float* h1g = ws + 8704;           // 2048
    float* h2g = ws + 10752;          // 2048
    float* gxt = ws + 16384;          // 128 x 8192
    float* gxa = ws + 16384 + 1048576;  // 16 x 8192

    // zero barrier counters + h buffers + h1/h2
    hipMemsetAsync(d_ws, 0, 51200, stream);
    gates_x_gemm<32><<<dim3(128, 4), 256, 0, stream>>>(x_t, emb_t, Wih_t, bih_t,
                                                       bhh_t, gxt);
    gates_x_gemm<16><<<dim3(128, 1), 256, 0, stream>>>(x_a, emb_a, Wih_a, bih_a,
                                                       bhh_a, gxa);
    lstm_mlp_persistent<<<NB, 512, 0, stream>>>(Whh_t, Whh_a, gxt, gxa, W1, b1,
                                                W2, b2, W3, b3, ctr, hbt, hba,
                                                h1g, h2g, (float*)d_out);
}

// Round 2
// 1639.086 us; speedup vs baseline: 1.8498x; 1.8498x over previous
//
#include <hip/hip_runtime.h>
#include <stdint.h>

#define NB 256    // persistent blocks == CUs
#define NBAR 160  // barrier instances (144 steps + 2 MLP + slack)

// ---------- fast math ----------
__device__ __forceinline__ float sigm(float x) {
    return 1.f / (1.f + __expf(-x));
}
__device__ __forceinline__ float tanh_fast(float x) {
    // 1 - 2/(e^{2x}+1): monotone, correct limits at +-inf
    return 1.f - 2.f / (__expf(2.f * x) + 1.f);
}

// ---------- RMW-free grid barrier ----------
// arrival: block b release-stores flags[idx*NB+b] (distinct words, no atomics)
// gather : block 0 threads 0..255 each poll one flag in parallel
// publish: block 0 tid 0 stores epochs[idx]; everyone polls it
__device__ __forceinline__ void gbar(unsigned* flags, unsigned* epochs, int idx) {
    __syncthreads();  // all waves drained (compiler emits vmcnt(0) before s_barrier)
    const int b = blockIdx.x;
    const int tid = threadIdx.x;
    unsigned* f = flags + idx * NB;
    if (tid == 0) {
        __builtin_amdgcn_fence(__ATOMIC_RELEASE, "agent");  // flush L2 (wbl2)
        __hip_atomic_store(&f[b], 1u, __ATOMIC_RELAXED, __HIP_MEMORY_SCOPE_AGENT);
    }
    if (b == 0) {
        if (tid < NB) {
            while (__hip_atomic_load(&f[tid], __ATOMIC_RELAXED,
                                     __HIP_MEMORY_SCOPE_AGENT) == 0u)
                __builtin_amdgcn_s_sleep(1);
        }
        __syncthreads();
        if (tid == 0) {
            __builtin_amdgcn_fence(__ATOMIC_RELEASE, "agent");
            __hip_atomic_store(&epochs[idx], 1u, __ATOMIC_RELAXED,
                               __HIP_MEMORY_SCOPE_AGENT);
        }
    }
    if (tid == 0) {
        while (__hip_atomic_load(&epochs[idx], __ATOMIC_RELAXED,
                                 __HIP_MEMORY_SCOPE_AGENT) == 0u)
            __builtin_amdgcn_s_sleep(1);
        __builtin_amdgcn_fence(__ATOMIC_ACQUIRE, "agent");  // inv L1+L2
    }
    __syncthreads();
}

// ---------- kernel G: Gx[t][j] = emb[idx[t]] . W_ih[j] + b_ih[j] + b_hh[j] ----------
template <int TT>
__global__ __launch_bounds__(256) void gates_x_gemm(
    const int* __restrict__ idx, const float* __restrict__ emb,
    const float* __restrict__ Wih, const float* __restrict__ bih,
    const float* __restrict__ bhh, float* __restrict__ Gx) {
    __shared__ float As[TT][36];
    __shared__ float Ws[32][68];  // [k][j], padded
    const int tid = threadIdx.x;
    const int jt = blockIdx.x * 64;
    const int t0 = blockIdx.y * TT;
    constexpr int TPT = TT / 16;
    const int tx = tid & 15, ty = tid >> 4;
    float acc[TPT][4];
#pragma unroll
    for (int a = 0; a < TPT; ++a)
#pragma unroll
        for (int q = 0; q < 4; ++q) acc[a][q] = 0.f;

    for (int k0 = 0; k0 < 1024; k0 += 32) {
        if constexpr (TT == 32) {
            int t = tid >> 3, kq = (tid & 7) * 4;
            int row = idx[t0 + t];
            float4 v = *(const float4*)(emb + (size_t)row * 1024 + k0 + kq);
            *(float4*)&As[t][kq] = v;
        } else {
            int t = tid >> 4, kq = (tid & 15) * 2;
            int row = idx[t0 + t];
            float2 v = *(const float2*)(emb + (size_t)row * 1024 + k0 + kq);
            *(float2*)&As[t][kq] = v;
        }
        {
            int j = tid >> 3, kq = (tid & 7) * 4;
            float4 w0 = *(const float4*)(Wih + (size_t)(jt + j) * 1024 + k0 + kq);
            float4 w1 = *(const float4*)(Wih + (size_t)(jt + j + 32) * 1024 + k0 + kq);
            const float* p0 = (const float*)&w0;
            const float* p1 = (const float*)&w1;
#pragma unroll
            for (int c = 0; c < 4; ++c) {
                Ws[kq + c][j] = p0[c];
                Ws[kq + c][j + 32] = p1[c];
            }
        }
        __syncthreads();
#pragma unroll
        for (int kk = 0; kk < 32; kk += 4) {
            float4 av[TPT];
#pragma unroll
            for (int tt = 0; tt < TPT; ++tt)
                av[tt] = *(float4*)&As[ty * TPT + tt][kk];
#pragma unroll
            for (int c = 0; c < 4; ++c) {
                float4 wv = *(float4*)&Ws[kk + c][tx * 4];
#pragma unroll
                for (int tt = 0; tt < TPT; ++tt) {
                    const float* ap = (const float*)&av[tt];
                    float a = ap[c];
                    acc[tt][0] += a * wv.x;
                    acc[tt][1] += a * wv.y;
                    acc[tt][2] += a * wv.z;
                    acc[tt][3] += a * wv.w;
                }
            }
        }
        __syncthreads();
    }
    int j = jt + tx * 4;
    float4 bi = *(const float4*)(bih + j);
    float4 bh = *(const float4*)(bhh + j);
#pragma unroll
    for (int tt = 0; tt < TPT; ++tt) {
        int t = t0 + ty * TPT + tt;
        float4 r;
        r.x = acc[tt][0] + bi.x + bh.x;
        r.y = acc[tt][1] + bi.y + bh.y;
        r.z = acc[tt][2] + bi.z + bh.z;
        r.w = acc[tt][3] + bi.w + bh.w;
        *(float4*)(Gx + (size_t)t * 8192 + j) = r;
    }
}

// ---------- kernel P: persistent LSTM scans + MLP head ----------
// 256 blocks x 512 threads; block b owns h rows [b*8, b*8+8) -> 32 gate rows.
// W_hh slice kept in REGISTERS (f32): thread (w,l) holds, for rows rl=w*4+r,
// k in {q*256 + l*4 .. +3}, q=0..7  -> 4x8 float4 = 128 VGPRs.
__global__ __launch_bounds__(512, 2) void lstm_mlp_persistent(
    const float* __restrict__ Whh_t, const float* __restrict__ Whh_a,
    const float* __restrict__ Gxt, const float* __restrict__ Gxa,
    const float* __restrict__ W1, const float* __restrict__ b1,
    const float* __restrict__ W2, const float* __restrict__ b2,
    const float* __restrict__ W3, const float* __restrict__ b3,
    unsigned* flags, unsigned* epochs, float* hbt, float* hba,
    float* h1g, float* h2g, float* out) {
    // 84 KB pad forces 1 block/CU so all 256 blocks are co-resident (barrier
    // safety); only the first 2048 floats are used for h staging.
    __shared__ float h_lds[21504];
    __shared__ float part_final[32];
    __shared__ float gsum[32];
    __shared__ float cl[8];
    const int tid = threadIdx.x;
    const int b = blockIdx.x;
    const int w = tid >> 6, l = tid & 63;
    int bar = 0;

    for (int scan = 0; scan < 2; ++scan) {
        const float* Whh = scan ? Whh_a : Whh_t;
        const float* Gx = scan ? Gxa : Gxt;
        float* hbuf = scan ? hba : hbt;
        const int T = scan ? 16 : 128;

        float4 wreg[4][8];
#pragma unroll
        for (int r = 0; r < 4; ++r) {
            const int rl = w * 4 + r;
            const int j = (rl >> 3) * 2048 + b * 8 + (rl & 7);
            const float* wrow = Whh + (size_t)j * 2048 + l * 4;
#pragma unroll
            for (int q = 0; q < 8; ++q) wreg[r][q] = *(const float4*)(wrow + q * 256);
        }
        if (tid < 8) cl[tid] = 0.f;

        for (int t = 0; t < T; ++t) {
            const float* hin = hbuf + (t & 1) * 2048;
            float* hout = hbuf + ((t + 1) & 1) * 2048;
            float gx;
            if (tid < 32)  // prefetch this step's x-gates early
                gx = Gx[(size_t)t * 8192 + (tid >> 3) * 2048 + b * 8 + (tid & 7)];
            *(float4*)(h_lds + tid * 4) = *(const float4*)(hin + tid * 4);
            __syncthreads();
            float4 hreg[8];
#pragma unroll
            for (int q = 0; q < 8; ++q) hreg[q] = *(float4*)(h_lds + q * 256 + l * 4);
            float acc[4];
#pragma unroll
            for (int r = 0; r < 4; ++r) {
                float a = 0.f;
#pragma unroll
                for (int q = 0; q < 8; ++q) {
                    a += wreg[r][q].x * hreg[q].x;
                    a += wreg[r][q].y * hreg[q].y;
                    a += wreg[r][q].z * hreg[q].z;
                    a += wreg[r][q].w * hreg[q].w;
                }
                acc[r] = a;
            }
#pragma unroll
            for (int r = 0; r < 4; ++r) {  // wave butterfly per row
                float a = acc[r];
#pragma unroll
                for (int off = 32; off; off >>= 1) a += __shfl_xor(a, off, 64);
                if (l == 0) part_final[w * 4 + r] = a;
            }
            __syncthreads();
            // wave 0 only below: in-order LDS ops within a wave, no extra sync
            if (tid < 32) gsum[tid] = part_final[tid] + gx;
            if (tid < 8) {
                float si = sigm(gsum[tid]);
                float sf = sigm(gsum[8 + tid]);
                float tg = tanh_fast(gsum[16 + tid]);
                float so = sigm(gsum[24 + tid]);
                float c = sf * cl[tid] + si * tg;
                cl[tid] = c;
                hout[b * 8 + tid] = so * tanh_fast(c);
            }
            gbar(flags, epochs, bar++);
        }
    }

    // ---- MLP head: summary = [h_title(2048), h_authors(2048)] ----
    {  // h1 = relu(W1 . summary + b1): row j per wave
        const int j = b * 8 + w;
        const float* wr = W1 + (size_t)j * 4096;
        float acc = 0.f;
#pragma unroll
        for (int i = 0; i < 8; ++i) {
            float4 wv = *(const float4*)(wr + i * 256 + l * 4);
            float4 hv = *(const float4*)(hbt + i * 256 + l * 4);
            acc += wv.x * hv.x + wv.y * hv.y + wv.z * hv.z + wv.w * hv.w;
        }
#pragma unroll
        for (int i = 0; i < 8; ++i) {
            float4 wv = *(const float4*)(wr + 2048 + i * 256 + l * 4);
            float4 hv = *(const float4*)(hba + i * 256 + l * 4);
            acc += wv.x * hv.x + wv.y * hv.y + wv.z * hv.z + wv.w * hv.w;
        }
#pragma unroll
        for (int off = 32; off; off >>= 1) acc += __shfl_xor(acc, off, 64);
        if (l == 0) h1g[j] = fmaxf(acc + b1[j], 0.f);
    }
    gbar(flags, epochs, bar++);
    {  // h2 = relu(W2 . h1 + b2)
        const int j = b * 8 + w;
        const float* wr = W2 + (size_t)j * 2048;
        float acc = 0.f;
#pragma unroll
        for (int i = 0; i < 8; ++i) {
            float4 wv = *(const float4*)(wr + i * 256 + l * 4);
            float4 hv = *(const float4*)(h1g + i * 256 + l * 4);
            acc += wv.x * hv.x + wv.y * hv.y + wv.z * hv.z + wv.w * hv.w;
        }
#pragma unroll
        for (int off = 32; off; off >>= 1) acc += __shfl_xor(acc, off, 64);
        if (l == 0) h2g[j] = fmaxf(acc + b2[j], 0.f);
    }
    gbar(flags, epochs, bar++);
    if (b == 0 && w < 2) {  // logits
        const float* wr = W3 + (size_t)w * 2048;
        float acc = 0.f;
#pragma unroll
        for (int i = 0; i < 8; ++i) {
            float4 wv = *(const float4*)(wr + i * 256 + l * 4);
            float4 hv = *(const float4*)(h2g + i * 256 + l * 4);
            acc += wv.x * hv.x + wv.y * hv.y + wv.z * hv.z + wv.w * hv.w;
        }
#pragma unroll
        for (int off = 32; off; off >>= 1) acc += __shfl_xor(acc, off, 64);
        if (l == 0) out[w] = acc + b3[w];
    }
}

extern "C" void kernel_launch(void* const* d_in, const int* in_sizes, int n_in,
                              void* d_out, int out_size, void* d_ws,
                              size_t ws_size, hipStream_t stream) {
    const int* x_t = (const int*)d_in[0];
    const int* x_a = (const int*)d_in[1];
    const float* emb_t = (const float*)d_in[2];
    const float* emb_a = (const float*)d_in[3];
    const float* Wih_t = (const float*)d_in[4];
    const float* Whh_t = (const float*)d_in[5];
    const float* bih_t = (const float*)d_in[6];
    const float* bhh_t = (const float*)d_in[7];
    const float* Wih_a = (const float*)d_in[8];
    const float* Whh_a = (const float*)d_in[9];
    const float* bih_a = (const float*)d_in[10];
    const float* bhh_a = (const float*)d_in[11];
    const float* W1 = (const float*)d_in[12];
    const float* b1 = (const float*)d_in[13];
    const float* W2 = (const float*)d_in[14];
    const float* b2 = (const float*)d_in[15];
    const float* W3 = (const float*)d_in[16];
    const float* b3 = (const float*)d_in[17];

    float* ws = (float*)d_ws;
    // layout (float offsets):
    unsigned* flags = (unsigned*)ws;          // 160*256 u32
    unsigned* epochs = (unsigned*)(ws + 40960);  // 160 u32
    float* hbt = ws + 41120;                  // 2 x 2048
    float* hba = ws + 45216;                  // 2 x 2048
    float* h1g = ws + 49312;                  // 2048
    float* h2g = ws + 51360;                  // 2048
    float* gxt = ws + 53408;                  // 128 x 8192
    float* gxa = ws + 53408 + 1048576;        // 16 x 8192

    // zero flags + epochs + h buffers + h1/h2 (bytes 0 .. 53408*4)
    hipMemsetAsync(d_ws, 0, 213632, stream);
    gates_x_gemm<32><<<dim3(128, 4), 256, 0, stream>>>(x_t, emb_t, Wih_t, bih_t,
                                                       bhh_t, gxt);
    gates_x_gemm<16><<<dim3(128, 1), 256, 0, stream>>>(x_a, emb_a, Wih_a, bih_a,
                                                       bhh_a, gxa);
    lstm_mlp_persistent<<<NB, 512, 0, stream>>>(Whh_t, Whh_a, gxt, gxa, W1, b1,
                                                W2, b2, W3, b3, flags, epochs,
                                                hbt, hba, h1g, h2g, (float*)d_out);
}